// Round 15
// baseline (169.459 us; speedup 1.0000x reference)
//
#include <hip/hip_runtime.h>

// PCEN: x (B=32, T=4000, C=128) fp32.
//   ema[t] = w*x[t] + (1-w)*ema[t-1],  ema[0] = x[0]
//   out = (x / (FLOOR + ema)^alpha + delta)^(1/root) - delta^(1/root)
//
// R18 (resubmitted R20 — two container infra failures, never measured):
// SINGLE-dispatch stripe kernel with EMA WARM-UP (scan eliminated).
// Evidence trail: dispatch-boundary scans plateau at ~133us (R6=R17);
// intra-dispatch sync is 10-50x worse (R12 grid.sync 838us, R15 lookback
// 2333us). R17 proved truncation is safe (absmax unchanged). The truncation
// is per-ELEMENT: (1-w)^tau, w=0.04 -> 0.96^256 = 2.9e-5; the EMA forgets
// beyond ~256 steps. So: block (b,s) owns a 250-step stripe and warms the
// recurrence from e=0 over the preceding <=256 rows (error ~1e-4 through
// the epilogue vs 6.6e-2 threshold), then computes its stripe exactly.
//   - ONE dispatch, NO workspace, NO cross-block data, x read 1.96x.
//   - loads/stores are coalesced 512B rows (R6: scalar rows == float4 here)
//   - unroll-16 warmup / unroll-4 main -> 8-16 outstanding loads/wave
//     (>=8KB in flight per CU vs ~6KB Little's-law need at 6.3TB/s)
//   - per-thread EXACT fallback (warm from t=0 with e=x[0]) when
//     omw^W > 3e-3 (adversarial w; never taken at w=0.04; also covers w=0)
// Grid: (NS=16 stripes) x (Bn=32) = 512 blocks x 128 thr = exactly 2/CU.

#define FLOOR_EPS 1e-12f

constexpr int Bn = 32;
constexpr int Tn = 4000;
constexpr int Cn = 128;
constexpr int NS      = 16;          // stripes per batch row
constexpr int LSTRIPE = Tn / NS;     // 250 timesteps per stripe
constexpr int HWARM   = 256;         // warm-up horizon (0.96^256 = 2.9e-5)

__global__ __launch_bounds__(Cn) void pcen_stripe(
    const float* __restrict__ x,
    const float* __restrict__ alpha_p,
    const float* __restrict__ delta_p,
    const float* __restrict__ root_p,
    const float* __restrict__ w_p,
    float* __restrict__ out)
{
    const int c  = threadIdx.x;                  // channel
    const int s  = blockIdx.x;                   // stripe 0..NS-1
    const int b  = blockIdx.y;                   // batch 0..Bn-1
    const int t0 = s * LSTRIPE;
    const int t1 = t0 + LSTRIPE;

    const float w   = fminf(fmaxf(w_p[c], 0.0f), 1.0f);
    const float omw = 1.0f - w;
    const float alpha  = fminf(alpha_p[c], 1.0f);
    const float root   = fmaxf(root_p[c], 1.0f);
    const float delta  = delta_p[c];
    const float oor    = 1.0f / root;
    const float droot  = __builtin_exp2f(oor * __builtin_log2f(delta));
    const float nalpha = -alpha;

    const float* __restrict__ xb = x   + (size_t)b * Tn * Cn + c;
    float* __restrict__       ob = out + (size_t)b * Tn * Cn + c;

    // ---- pick warm-up start (per-thread; no block coordination needed) ----
    int   ts;                                    // first t fed to recurrence
    float e;                                     // ema carry BEFORE step ts
    if (t0 == 0) {
        ts = 0; e = xb[0];                       // exact init: ema[-1] := x[0]
    } else {
        const int   W = (t0 < HWARM) ? t0 : HWARM;
        // decay = omw^W  (omw=0 -> log2=-inf -> 0, fine; omw=1 -> 1)
        const float decay = __builtin_exp2f((float)W * __builtin_log2f(omw));
        if (decay > 3e-3f) { ts = 0;      e = xb[0]; }   // exact (adversarial)
        else               { ts = t0 - W; e = 0.0f;  }   // truncated warm-up
    }

    // ---- warm-up [ts, t0): recurrence only; 16 indep loads in flight ----
    const float* xq = xb + (size_t)ts * Cn;
    int t = ts;
    for (; t + 16 <= t0; t += 16) {
        float v[16];
        #pragma unroll
        for (int k = 0; k < 16; ++k) v[k] = xq[(size_t)k * Cn];
        #pragma unroll
        for (int k = 0; k < 16; ++k) e = fmaf(omw, e, w * v[k]);
        xq += (size_t)16 * Cn;
    }
    for (; t < t0; ++t) { e = fmaf(omw, e, w * xq[0]); xq += Cn; }

    // ---- main [t0, t1): recurrence + verified epilogue + coalesced store --
    float* oq = ob + (size_t)t0 * Cn;
    for (t = t0; t + 4 <= t1; t += 4) {
        float v[4];
        #pragma unroll
        for (int k = 0; k < 4; ++k) v[k] = xq[(size_t)k * Cn];
        #pragma unroll
        for (int k = 0; k < 4; ++k) {
            e = fmaf(omw, e, w * v[k]);
            const float l  = __builtin_log2f(FLOOR_EPS + e);
            const float tv = v[k] * __builtin_exp2f(nalpha * l);
            oq[(size_t)k * Cn] =
                __builtin_exp2f(oor * __builtin_log2f(tv + delta)) - droot;
        }
        xq += (size_t)4 * Cn;
        oq += (size_t)4 * Cn;
    }
    for (; t < t1; ++t) {                        // LSTRIPE%4==2 remainder
        const float xv = xq[0];
        e = fmaf(omw, e, w * xv);
        const float l  = __builtin_log2f(FLOOR_EPS + e);
        const float tv = xv * __builtin_exp2f(nalpha * l);
        oq[0] = __builtin_exp2f(oor * __builtin_log2f(tv + delta)) - droot;
        xq += Cn; oq += Cn;
    }
}

extern "C" void kernel_launch(void* const* d_in, const int* in_sizes, int n_in,
                              void* d_out, int out_size, void* d_ws, size_t ws_size,
                              hipStream_t stream) {
    const float* x     = (const float*)d_in[0];
    const float* alpha = (const float*)d_in[1];
    const float* delta = (const float*)d_in[2];
    const float* root  = (const float*)d_in[3];
    const float* ew    = (const float*)d_in[4];
    float* out = (float*)d_out;

    pcen_stripe<<<dim3(NS, Bn), Cn, 0, stream>>>(x, alpha, delta, root, ew, out);
}

// Round 16
// 143.030 us; speedup vs baseline: 1.1848x; 1.1848x over previous
//
#include <hip/hip_runtime.h>

// PCEN: x (B=32, T=4000, C=128) fp32.
//   ema[t] = w*x[t] + (1-w)*ema[t-1],  ema[0] = x[0]
//   out = (x / (FLOOR + ema)^alpha + delta)^(1/root) - delta^(1/root)
//
// R21: stripe kernel v2 — MLP-restructured (R18 post-mortem).
// R18 measured: 82.6us kernel, 1.57TB/s, occ 7%, VGPR=16. VGPR=16 proves the
// compiler folded every load into the serial EMA chain (1 outstanding load!)
// -> pure latency bound. Fixes:
//   (1) warm-up batches of 16 with precomputed weights wk[r]=w*omw^(15-r):
//       16 INDEPENDENT fmas into 4 accumulators + one acc=acc*omw^16+bsum
//       per batch -> loads must be clustered (regfile holds v[16]+wk[16])
//   (2) main loop software-pipelined: prefetch nv[8] before processing v[8]
//   (3) NS 16->32 stripes (1024 blocks, 8 waves/CU; >=16KB in flight/CU)
// Warm-up re-reads are cache-absorbed (R18: FETCH=62.7MB ~ compulsory).
// Exactness: batch decomposition is algebraically identical to the serial
// fold; truncation class verified by R17/R18 (absmax 0.0039 unchanged).
// Edge cases: w=0 (wk=0, acc stays e_init), w=1 (omw=0: only wk[15]=1,
// W16=0 -> acc=x[last]), adversarial small-w -> exact path from t=0.
// Grid: (NS=32) x (Bn=32) = 1024 blocks x 128 thr.

#define FLOOR_EPS 1e-12f

constexpr int Bn = 32;
constexpr int Tn = 4000;
constexpr int Cn = 128;
constexpr int NS      = 32;          // stripes per batch row
constexpr int LSTRIPE = Tn / NS;     // 125 timesteps per stripe
constexpr int HWARM   = 256;         // warm-up horizon (0.96^256 = 2.9e-5)

__global__ __launch_bounds__(Cn) void pcen_stripe(
    const float* __restrict__ x,
    const float* __restrict__ alpha_p,
    const float* __restrict__ delta_p,
    const float* __restrict__ root_p,
    const float* __restrict__ w_p,
    float* __restrict__ out)
{
    const int c  = threadIdx.x;                  // channel
    const int s  = blockIdx.x;                   // stripe 0..NS-1
    const int b  = blockIdx.y;                   // batch 0..Bn-1
    const int t0 = s * LSTRIPE;
    const int t1 = t0 + LSTRIPE;

    const float w   = fminf(fmaxf(w_p[c], 0.0f), 1.0f);
    const float omw = 1.0f - w;
    const float alpha  = fminf(alpha_p[c], 1.0f);
    const float root   = fmaxf(root_p[c], 1.0f);
    const float delta  = delta_p[c];
    const float oor    = 1.0f / root;
    const float droot  = __builtin_exp2f(oor * __builtin_log2f(delta));
    const float nalpha = -alpha;

    const float* __restrict__ xb = x   + (size_t)b * Tn * Cn + c;
    float* __restrict__       ob = out + (size_t)b * Tn * Cn + c;

    // ---- pick warm-up start (per-thread; no block coordination) ----
    int   ts;                                    // first t fed to recurrence
    float acc;                                   // ema carry BEFORE step ts
    if (t0 == 0) {
        ts = 0; acc = xb[0];                     // exact init: ema[-1] := x[0]
    } else {
        const int   W = (t0 < HWARM) ? t0 : HWARM;
        // decay = omw^W (omw=0 -> log2=-inf -> 0, fine; omw=1 -> 1)
        const float decay = __builtin_exp2f((float)W * __builtin_log2f(omw));
        if (decay > 3e-3f) { ts = 0;      acc = xb[0]; }  // exact (advers.)
        else               { ts = t0 - W; acc = 0.0f;  }  // truncated
    }

    // batch weights: wk[r] = w * omw^(15-r);  W16 = omw^16
    float wk[16];
    wk[15] = w;
    #pragma unroll
    for (int r = 14; r >= 0; --r) wk[r] = wk[r + 1] * omw;
    const float o2 = omw * omw, o4 = o2 * o2, o8 = o4 * o4;
    const float W16 = o8 * o8;

    // ---- warm-up [ts, t0): remainder first (chronological), then batches --
    const float* xq = xb + (size_t)ts * Cn;
    const int wn   = t0 - ts;
    const int nrem = wn & 15;
    {
        float rv[16];
        #pragma unroll
        for (int k = 0; k < 16; ++k)
            rv[k] = (k < nrem) ? xq[(size_t)k * Cn] : 0.0f;   // preloaded
        #pragma unroll
        for (int k = 0; k < 16; ++k)
            if (k < nrem) acc = fmaf(omw, acc, w * rv[k]);
        xq += (size_t)nrem * Cn;
    }
    const int nb = wn >> 4;                      // 16-row batches
    for (int bi = 0; bi < nb; ++bi) {
        float v[16];
        #pragma unroll
        for (int k = 0; k < 16; ++k) v[k] = xq[(size_t)k * Cn];  // clustered
        float s0 = 0.0f, s1 = 0.0f, s2 = 0.0f, s3 = 0.0f;
        #pragma unroll
        for (int k = 0; k < 16; k += 4) {        // independent FMA trees
            s0 = fmaf(wk[k],     v[k],     s0);
            s1 = fmaf(wk[k + 1], v[k + 1], s1);
            s2 = fmaf(wk[k + 2], v[k + 2], s2);
            s3 = fmaf(wk[k + 3], v[k + 3], s3);
        }
        acc = fmaf(acc, W16, (s0 + s1) + (s2 + s3));
        xq += (size_t)16 * Cn;
    }
    float e = acc;                               // ema state entering chunk

    // ---- main [t0, t1): software-pipelined batches of 8 ----
    // LSTRIPE = 125 = 15*8 + 5
    float* oq = ob + (size_t)t0 * Cn;
    float v[8];
    #pragma unroll
    for (int k = 0; k < 8; ++k) v[k] = xq[(size_t)k * Cn];
    xq += (size_t)8 * Cn;                        // -> row t0+8
    for (int bi = 0; bi < 15; ++bi) {
        float nv[8];
        if (bi < 14) {                           // prefetch next batch
            #pragma unroll
            for (int k = 0; k < 8; ++k) nv[k] = xq[(size_t)k * Cn];
        }
        #pragma unroll
        for (int k = 0; k < 8; ++k) {
            e = fmaf(omw, e, w * v[k]);
            const float l  = __builtin_log2f(FLOOR_EPS + e);
            const float tv = v[k] * __builtin_exp2f(nalpha * l);
            oq[(size_t)k * Cn] =
                __builtin_exp2f(oor * __builtin_log2f(tv + delta)) - droot;
        }
        oq += (size_t)8 * Cn;
        if (bi < 14) {
            #pragma unroll
            for (int k = 0; k < 8; ++k) v[k] = nv[k];
            xq += (size_t)8 * Cn;
        }
    }
    {   // tail 5 rows (t0+120 .. t0+124), preloaded
        float tv5[5];
        #pragma unroll
        for (int k = 0; k < 5; ++k) tv5[k] = xq[(size_t)k * Cn];
        #pragma unroll
        for (int k = 0; k < 5; ++k) {
            e = fmaf(omw, e, w * tv5[k]);
            const float l  = __builtin_log2f(FLOOR_EPS + e);
            const float tv = tv5[k] * __builtin_exp2f(nalpha * l);
            oq[(size_t)k * Cn] =
                __builtin_exp2f(oor * __builtin_log2f(tv + delta)) - droot;
        }
    }
}

extern "C" void kernel_launch(void* const* d_in, const int* in_sizes, int n_in,
                              void* d_out, int out_size, void* d_ws, size_t ws_size,
                              hipStream_t stream) {
    const float* x     = (const float*)d_in[0];
    const float* alpha = (const float*)d_in[1];
    const float* delta = (const float*)d_in[2];
    const float* root  = (const float*)d_in[3];
    const float* ew    = (const float*)d_in[4];
    float* out = (float*)d_out;

    pcen_stripe<<<dim3(NS, Bn), Cn, 0, stream>>>(x, alpha, delta, root, ew, out);
}